// Round 3
// baseline (305.048 us; speedup 1.0000x reference)
//
#include <hip/hip_runtime.h>
#include <stdint.h>

typedef unsigned short u16;
typedef __attribute__((ext_vector_type(8))) short short8_t;
typedef __attribute__((ext_vector_type(4))) float f32x4;

#define D_DIM 512
#define K_CL  256
#define BM    128
#define BK    64
#define NSTEP (D_DIM / BK)   // 8

__device__ __forceinline__ u16 f2bf(float f) {
  union { float f; uint32_t u; } v; v.f = f;
  uint32_t r = v.u + 0x7fffu + ((v.u >> 16) & 1u);  // RNE
  return (u16)(r >> 16);
}

__device__ __forceinline__ short8_t pack8(float4 f0, float4 f1) {
  union { u16 u[8]; short8_t v; } pk;
  pk.u[0] = f2bf(f0.x); pk.u[1] = f2bf(f0.y);
  pk.u[2] = f2bf(f0.z); pk.u[3] = f2bf(f0.w);
  pk.u[4] = f2bf(f1.x); pk.u[5] = f2bf(f1.y);
  pk.u[6] = f2bf(f1.z); pk.u[7] = f2bf(f1.w);
  return pk.v;
}

// prep: clusters fp32 [256][512] -> bf16 cb [256][512] + csq[256] (fp32 norms)
__global__ void prep_kernel(const float* __restrict__ clusters,
                            u16* __restrict__ cb, float* __restrict__ csq) {
  int k = blockIdx.x;
  int t = threadIdx.x;  // 128 threads, 4 floats each
  float4 f = ((const float4*)(clusters + (size_t)k * D_DIM))[t];
  ushort4 u;
  u.x = f2bf(f.x); u.y = f2bf(f.y); u.z = f2bf(f.z); u.w = f2bf(f.w);
  ((ushort4*)(cb + (size_t)k * D_DIM))[t] = u;
  float s = f.x*f.x + f.y*f.y + f.z*f.z + f.w*f.w;
  #pragma unroll
  for (int m = 1; m < 64; m <<= 1) s += __shfl_xor(s, m, 64);
  __shared__ float part[2];
  if ((t & 63) == 0) part[t >> 6] = s;
  __syncthreads();
  if (t == 0) csq[k] = part[0] + part[1];
}

// main: 8 independent waves per block, each owning 16 rows x 256 cols.
// A: global -> registers -> bf16 frags. B: global(L1/L2-resident) -> registers.
// No LDS, no barriers, no staging pipeline.
__global__ __launch_bounds__(512, 4)
void cluster_kernel(const float* __restrict__ x,
                    const u16* __restrict__ cb,
                    const float* __restrict__ csq,
                    float* __restrict__ out) {
  const int tid  = threadIdx.x;
  const int lane = tid & 63;
  const int w    = tid >> 6;          // wave 0..7 -> 16-row stripe
  const int l16  = lane & 15;
  const int quad = lane >> 4;
  const int row0 = blockIdx.x * BM;

  // ---- A: lane covers row (w*16+l16), k-slice quad*8 (+0 / +32) ----
  const int arow = row0 + w * 16 + l16;
  const float4* xg = (const float4*)(x + (size_t)arow * D_DIM + quad * 8);

  // ---- B fragment base: lane = cluster row (ni*16+l16), k = quad*8 + k32*32.
  // byte addr = (ni*16+l16)*1024 + quad*16 + k32*64 + step*128 ----
  const char* bbase = (const char*)cb + l16 * 1024 + quad * 16;

  f32x4 acc[16];
  #pragma unroll
  for (int i = 0; i < 16; ++i) acc[i] = (f32x4){0.f, 0.f, 0.f, 0.f};

  float4 a0 = xg[0], a1 = xg[1], a2 = xg[8], a3 = xg[9];
  float sq = 0.f;

  for (int step = 0; step < NSTEP; ++step) {
    // convert current A regs -> frags, accumulate ||x||^2 from fp32
    sq += a0.x*a0.x + a0.y*a0.y + a0.z*a0.z + a0.w*a0.w
        + a1.x*a1.x + a1.y*a1.y + a1.z*a1.z + a1.w*a1.w
        + a2.x*a2.x + a2.y*a2.y + a2.z*a2.z + a2.w*a2.w
        + a3.x*a3.x + a3.y*a3.y + a3.z*a3.z + a3.w*a3.w;
    short8_t aF0 = pack8(a0, a1);
    short8_t aF1 = pack8(a2, a3);

    if (step + 1 < NSTEP) {       // prefetch next A (hides HBM latency under MFMA)
      xg += 16;
      a0 = xg[0]; a1 = xg[1]; a2 = xg[8]; a3 = xg[9];
    }

    const char* bp = bbase + step * 128;
    #pragma unroll
    for (int ni = 0; ni < 16; ++ni) {
      short8_t b0 = *(const short8_t*)(bp + ni * 16384);       // k32 = 0
      short8_t b1 = *(const short8_t*)(bp + ni * 16384 + 64);  // k32 = 1
      acc[ni] = __builtin_amdgcn_mfma_f32_16x16x32_bf16(aF0, b0, acc[ni], 0, 0, 0);
      acc[ni] = __builtin_amdgcn_mfma_f32_16x16x32_bf16(aF1, b1, acc[ni], 0, 0, 0);
    }
  }

  // ---- epilogue (wave-local: no barriers, no LDS) ----
  sq += __shfl_xor(sq, 16, 64);
  sq += __shfl_xor(sq, 32, 64);
  // C layout: row = quad*4 + v, col = ni*16 + l16 -> need sq of rows quad*4+v
  float xs[4];
  #pragma unroll
  for (int v = 0; v < 4; ++v)
    xs[v] = __shfl(sq, quad * 4 + v, 64);

  float cs[16];
  #pragma unroll
  for (int ni = 0; ni < 16; ++ni) cs[ni] = csq[ni * 16 + l16];

  float rs[4] = {0.f, 0.f, 0.f, 0.f};
  #pragma unroll
  for (int ni = 0; ni < 16; ++ni) {
    #pragma unroll
    for (int v = 0; v < 4; ++v) {
      float d = xs[v] + cs[ni] - 2.0f * acc[ni][v];
      d = fmaxf(d, 0.f);
      float qv = __builtin_amdgcn_rcpf(1.0f + d);   // alpha=1: (1+d^2)^-1
      acc[ni][v] = qv;
      rs[v] += qv;
    }
  }
  #pragma unroll
  for (int v = 0; v < 4; ++v) {
    rs[v] += __shfl_xor(rs[v], 1, 64);
    rs[v] += __shfl_xor(rs[v], 2, 64);
    rs[v] += __shfl_xor(rs[v], 4, 64);
    rs[v] += __shfl_xor(rs[v], 8, 64);
    rs[v] = __builtin_amdgcn_rcpf(rs[v]);
  }
  #pragma unroll
  for (int v = 0; v < 4; ++v) {
    float* orow = out + (size_t)(row0 + w * 16 + quad * 4 + v) * K_CL;
    #pragma unroll
    for (int ni = 0; ni < 16; ++ni)
      orow[ni * 16 + l16] = acc[ni][v] * rs[v];
  }
}

extern "C" void kernel_launch(void* const* d_in, const int* in_sizes, int n_in,
                              void* d_out, int out_size, void* d_ws, size_t ws_size,
                              hipStream_t stream) {
  const float* x        = (const float*)d_in[0];
  const float* clusters = (const float*)d_in[1];
  float* out = (float*)d_out;
  const int N = in_sizes[0] / D_DIM;   // 65536

  u16*   cb  = (u16*)d_ws;                                    // 256*512*2 = 256 KB
  float* csq = (float*)((char*)d_ws + (size_t)K_CL * D_DIM * sizeof(u16));

  prep_kernel<<<K_CL, 128, 0, stream>>>(clusters, cb, csq);
  cluster_kernel<<<N / BM, 512, 0, stream>>>(x, cb, csq, out);
}

// Round 4
// 216.997 us; speedup vs baseline: 1.4058x; 1.4058x over previous
//
#include <hip/hip_runtime.h>
#include <stdint.h>

typedef unsigned short u16;
typedef __attribute__((ext_vector_type(8))) short short8_t;
typedef __attribute__((ext_vector_type(4))) float f32x4;

#define D_DIM 512
#define K_CL  256
#define BM    128
#define BK    64
#define NSTEP (D_DIM / BK)   // 8

__device__ __forceinline__ u16 f2bf(float f) {
  union { float f; uint32_t u; } v; v.f = f;
  uint32_t r = v.u + 0x7fffu + ((v.u >> 16) & 1u);  // RNE
  return (u16)(r >> 16);
}

__device__ __forceinline__ short8_t pack8(float4 f0, float4 f1) {
  union { u16 u[8]; short8_t v; } pk;
  pk.u[0] = f2bf(f0.x); pk.u[1] = f2bf(f0.y);
  pk.u[2] = f2bf(f0.z); pk.u[3] = f2bf(f0.w);
  pk.u[4] = f2bf(f1.x); pk.u[5] = f2bf(f1.y);
  pk.u[6] = f2bf(f1.z); pk.u[7] = f2bf(f1.w);
  return pk.v;
}

// prep: clusters fp32 [256][512] -> bf16 cb [256][512] + csq[256] (fp32 norms)
__global__ void prep_kernel(const float* __restrict__ clusters,
                            u16* __restrict__ cb, float* __restrict__ csq) {
  int k = blockIdx.x;
  int t = threadIdx.x;  // 128 threads, 4 floats each
  float4 f = ((const float4*)(clusters + (size_t)k * D_DIM))[t];
  ushort4 u;
  u.x = f2bf(f.x); u.y = f2bf(f.y); u.z = f2bf(f.z); u.w = f2bf(f.w);
  ((ushort4*)(cb + (size_t)k * D_DIM))[t] = u;
  float s = f.x*f.x + f.y*f.y + f.z*f.z + f.w*f.w;
  #pragma unroll
  for (int m = 1; m < 64; m <<= 1) s += __shfl_xor(s, m, 64);
  __shared__ float part[2];
  if ((t & 63) == 0) part[t >> 6] = s;
  __syncthreads();
  if (t == 0) csq[k] = part[0] + part[1];
}

// main: 4 waves/block, each wave owns 32 rows x 256 cols (M-rep 2 -> each
// B fragment feeds 4 MFMAs, halving LDS read traffic vs 16-row waves).
// A: global->reg->bf16 frags. B: LDS double-buffer, global_load_lds w=16,
// linear dest + pre-swizzled source + swizzled ds_read (verified R1 scheme).
__global__ __launch_bounds__(256, 2)
void cluster_kernel(const float* __restrict__ x,
                    const u16* __restrict__ cb,
                    const float* __restrict__ csq,
                    float* __restrict__ out) {
  __shared__ u16 lB[2 * K_CL * BK];   // 64 KB double buffer

  const int tid  = threadIdx.x;       // 256 threads
  const int lane = tid & 63;
  const int w    = tid >> 6;          // wave 0..3 -> 32-row stripe
  const int l16  = lane & 15;
  const int quad = lane >> 4;
  const int row0 = blockIdx.x * BM;

  // ---- A: lane covers rows (w*32+l16) and (w*32+16+l16), k-slice quad*8 ----
  const float4* xg0 = (const float4*)(x + (size_t)(row0 + w * 32 + l16) * D_DIM + quad * 8);
  const float4* xg1 = xg0 + 16 * (D_DIM / 4);   // +16 rows

  // ---- B staging source (pre-swizzled; dest stays linear) ----
  // dest byte o = i*4096 + tid*16 (i=0..7); row n = o>>7 = (tid>>3) + i*32;
  // in-row kb = (tid&7)*16; swizzled source kb' = kb ^ ((n&7)<<4); n&7 inv. in i.
  const int kbp = ((tid & 7) * 16) ^ (((tid >> 3) & 7) * 16);
  const u16* sp = cb + (size_t)(tid >> 3) * D_DIM + (kbp >> 1);

  // ---- swizzled ds_read byte offsets (verified R1 math) ----
  const int c3 = (l16 & 3) << 4;
  const int h  = (l16 & 4) << 4;
  const int p  = l16 * 128 + ((quad * 16) ^ c3);
  const int p0 = p + h;           // k32 = 0
  const int p1 = p + (h ^ 64);    // k32 = 1

  f32x4 acc[2][16];
  #pragma unroll
  for (int mi = 0; mi < 2; ++mi)
    #pragma unroll
    for (int i = 0; i < 16; ++i) acc[mi][i] = (f32x4){0.f, 0.f, 0.f, 0.f};

  // ---- prologue: stage step 0 into buf0, load A step 0 ----
  {
    char* dstb = (char*)lB + tid * 16;
    #pragma unroll
    for (int i = 0; i < 8; ++i)
      __builtin_amdgcn_global_load_lds(
          (const __attribute__((address_space(1))) void*)(sp + i * 16384),
          (__attribute__((address_space(3))) void*)(dstb + i * 4096), 16, 0, 0);
  }
  float4 a00 = xg0[0], a01 = xg0[1], a02 = xg0[8], a03 = xg0[9];
  float4 a10 = xg1[0], a11 = xg1[1], a12 = xg1[8], a13 = xg1[9];

  float sq0 = 0.f, sq1 = 0.f;

  for (int step = 0; step < NSTEP; ++step) {
    __syncthreads();   // buf[step&1] staged; buf[step&1 ^ 1] free

    sq0 += a00.x*a00.x + a00.y*a00.y + a00.z*a00.z + a00.w*a00.w
         + a01.x*a01.x + a01.y*a01.y + a01.z*a01.z + a01.w*a01.w
         + a02.x*a02.x + a02.y*a02.y + a02.z*a02.z + a02.w*a02.w
         + a03.x*a03.x + a03.y*a03.y + a03.z*a03.z + a03.w*a03.w;
    sq1 += a10.x*a10.x + a10.y*a10.y + a10.z*a10.z + a10.w*a10.w
         + a11.x*a11.x + a11.y*a11.y + a11.z*a11.z + a11.w*a11.w
         + a12.x*a12.x + a12.y*a12.y + a12.z*a12.z + a12.w*a12.w
         + a13.x*a13.x + a13.y*a13.y + a13.z*a13.z + a13.w*a13.w;
    short8_t aF00 = pack8(a00, a01);   // rows w*32+l16,    k 0..31
    short8_t aF01 = pack8(a02, a03);   //                   k 32..63
    short8_t aF10 = pack8(a10, a11);   // rows w*32+16+l16, k 0..31
    short8_t aF11 = pack8(a12, a13);   //                   k 32..63

    if (step + 1 < NSTEP) {
      // stage next B into other buffer
      const u16* spq = sp + (step + 1) * BK;
      char* dstb = (char*)lB + (((step + 1) & 1) << 15) + tid * 16;
      #pragma unroll
      for (int i = 0; i < 8; ++i)
        __builtin_amdgcn_global_load_lds(
            (const __attribute__((address_space(1))) void*)(spq + i * 16384),
            (__attribute__((address_space(3))) void*)(dstb + i * 4096), 16, 0, 0);
      // prefetch next A
      xg0 += 16; xg1 += 16;
      a00 = xg0[0]; a01 = xg0[1]; a02 = xg0[8]; a03 = xg0[9];
      a10 = xg1[0]; a11 = xg1[1]; a12 = xg1[8]; a13 = xg1[9];
    }

    // B frags from swizzled LDS: 32 ds_read_b128 feed 64 MFMAs (1:2)
    const char* pb = (const char*)lB + ((step & 1) << 15);
    #pragma unroll
    for (int ni = 0; ni < 16; ++ni) {
      short8_t b0 = *(const short8_t*)(pb + ni * 2048 + p0);   // k32 = 0
      short8_t b1 = *(const short8_t*)(pb + ni * 2048 + p1);   // k32 = 1
      acc[0][ni] = __builtin_amdgcn_mfma_f32_16x16x32_bf16(aF00, b0, acc[0][ni], 0, 0, 0);
      acc[0][ni] = __builtin_amdgcn_mfma_f32_16x16x32_bf16(aF01, b1, acc[0][ni], 0, 0, 0);
      acc[1][ni] = __builtin_amdgcn_mfma_f32_16x16x32_bf16(aF10, b0, acc[1][ni], 0, 0, 0);
      acc[1][ni] = __builtin_amdgcn_mfma_f32_16x16x32_bf16(aF11, b1, acc[1][ni], 0, 0, 0);
    }
  }

  // ---- epilogue (wave-local) ----
  sq0 += __shfl_xor(sq0, 16, 64); sq0 += __shfl_xor(sq0, 32, 64);
  sq1 += __shfl_xor(sq1, 16, 64); sq1 += __shfl_xor(sq1, 32, 64);
  // C layout: row = mi*16 + quad*4 + v, col = ni*16 + l16
  float xs[2][4];
  #pragma unroll
  for (int v = 0; v < 4; ++v) {
    xs[0][v] = __shfl(sq0, quad * 4 + v, 64);
    xs[1][v] = __shfl(sq1, quad * 4 + v, 64);
  }

  float cs[16];
  #pragma unroll
  for (int ni = 0; ni < 16; ++ni) cs[ni] = csq[ni * 16 + l16];

  #pragma unroll
  for (int mi = 0; mi < 2; ++mi) {
    float rs[4] = {0.f, 0.f, 0.f, 0.f};
    #pragma unroll
    for (int ni = 0; ni < 16; ++ni) {
      #pragma unroll
      for (int v = 0; v < 4; ++v) {
        float d = xs[mi][v] + cs[ni] - 2.0f * acc[mi][ni][v];
        d = fmaxf(d, 0.f);
        float qv = __builtin_amdgcn_rcpf(1.0f + d);   // alpha=1: (1+d^2)^-1
        acc[mi][ni][v] = qv;
        rs[v] += qv;
      }
    }
    #pragma unroll
    for (int v = 0; v < 4; ++v) {
      rs[v] += __shfl_xor(rs[v], 1, 64);
      rs[v] += __shfl_xor(rs[v], 2, 64);
      rs[v] += __shfl_xor(rs[v], 4, 64);
      rs[v] += __shfl_xor(rs[v], 8, 64);
      rs[v] = __builtin_amdgcn_rcpf(rs[v]);
    }
    #pragma unroll
    for (int v = 0; v < 4; ++v) {
      float* orow = out + (size_t)(row0 + w * 32 + mi * 16 + quad * 4 + v) * K_CL;
      #pragma unroll
      for (int ni = 0; ni < 16; ++ni)
        orow[ni * 16 + l16] = acc[mi][ni][v] * rs[v];
    }
  }
}

extern "C" void kernel_launch(void* const* d_in, const int* in_sizes, int n_in,
                              void* d_out, int out_size, void* d_ws, size_t ws_size,
                              hipStream_t stream) {
  const float* x        = (const float*)d_in[0];
  const float* clusters = (const float*)d_in[1];
  float* out = (float*)d_out;
  const int N = in_sizes[0] / D_DIM;   // 65536

  u16*   cb  = (u16*)d_ws;                                    // 256*512*2 = 256 KB
  float* csq = (float*)((char*)d_ws + (size_t)K_CL * D_DIM * sizeof(u16));

  prep_kernel<<<K_CL, 128, 0, stream>>>(clusters, cb, csq);
  cluster_kernel<<<N / BM, 256, 0, stream>>>(x, cb, csq, out);
}